// Round 1
// baseline (2219.708 us; speedup 1.0000x reference)
//
#include <hip/hip_runtime.h>
#include <cstddef>

#define BB 4
#define SS 2304      // 48*48
#define FF 512
#define NH 8
#define DD 64
#define BSR (BB*SS)  // 9216 rows
#define QROWS 8
#define LSTRIDE 2308 // 2304 + 4 (bank-conflict break)

// ---------------------------------------------------------------------------
// Projection GEMM: out = X @ W + b.  X:[BSR][FF] row-major, W:[FF][FF] row-major.
// 64x64 tile per block, 256 threads, 4x4 micro-tile per thread, K-step 16.
// head_split=1: write out[((b*NH+head)*SS + s)*DD + dd]  (head = col/64)
// head_split=0: write out[row*FF + col]
// ---------------------------------------------------------------------------
__global__ __launch_bounds__(256) void proj_kernel(
    const float* __restrict__ X, const float* __restrict__ Wm,
    const float* __restrict__ bias, float* __restrict__ out, int head_split)
{
    __shared__ __align__(16) float Ast[16][68];  // transposed A tile [k][row]
    __shared__ __align__(16) float Bs[16][68];   // B tile [k][col]

    const int t  = threadIdx.x;
    const int i0 = blockIdx.x * 64;
    const int j0 = blockIdx.y * 64;
    const int tr = t >> 4;       // 0..15 (row group)
    const int tc = t & 15;       // 0..15 (col group)

    float4 acc[4];
    #pragma unroll
    for (int i = 0; i < 4; ++i) acc[i] = make_float4(0.f, 0.f, 0.f, 0.f);

    const int lrow = t >> 2;     // 0..63  (A load row)
    const int lcg  = t & 3;      // 0..3   (A load col group of 4)
    const int brow = t >> 4;     // 0..15  (B load row)
    const int bcg  = t & 15;     // 0..15  (B load col group of 4)

    for (int kk = 0; kk < FF; kk += 16) {
        // load + transpose A tile: X[i0+lrow][kk + 4*lcg .. +3]
        float4 a = *(const float4*)&X[(size_t)(i0 + lrow) * FF + kk + 4 * lcg];
        Ast[4 * lcg + 0][lrow] = a.x;
        Ast[4 * lcg + 1][lrow] = a.y;
        Ast[4 * lcg + 2][lrow] = a.z;
        Ast[4 * lcg + 3][lrow] = a.w;
        // load B tile: W[kk+brow][j0 + 4*bcg .. +3]
        float4 b = *(const float4*)&Wm[(size_t)(kk + brow) * FF + j0 + 4 * bcg];
        *(float4*)&Bs[brow][4 * bcg] = b;
        __syncthreads();
        #pragma unroll
        for (int k = 0; k < 16; ++k) {
            float4 av = *(const float4*)&Ast[k][4 * tr];
            float4 bv = *(const float4*)&Bs[k][4 * tc];
            acc[0].x += av.x * bv.x; acc[0].y += av.x * bv.y; acc[0].z += av.x * bv.z; acc[0].w += av.x * bv.w;
            acc[1].x += av.y * bv.x; acc[1].y += av.y * bv.y; acc[1].z += av.y * bv.z; acc[1].w += av.y * bv.w;
            acc[2].x += av.z * bv.x; acc[2].y += av.z * bv.y; acc[2].z += av.z * bv.z; acc[2].w += av.z * bv.w;
            acc[3].x += av.w * bv.x; acc[3].y += av.w * bv.y; acc[3].z += av.w * bv.z; acc[3].w += av.w * bv.w;
        }
        __syncthreads();
    }

    float4 bb = *(const float4*)&bias[j0 + 4 * tc];
    #pragma unroll
    for (int i = 0; i < 4; ++i) {
        const int row = i0 + 4 * tr + i;
        float4 o = make_float4(acc[i].x + bb.x, acc[i].y + bb.y,
                               acc[i].z + bb.z, acc[i].w + bb.w);
        if (head_split) {
            const int bidx = row / SS;
            const int s    = row - bidx * SS;
            const int head = j0 >> 6;
            *(float4*)&out[(((size_t)bidx * NH + head) * SS + s) * DD + 4 * tc] = o;
        } else {
            *(float4*)&out[(size_t)row * FF + j0 + 4 * tc] = o;
        }
    }
}

// ---------------------------------------------------------------------------
// Attention: per block = (q-tile of 8 rows, head, batch).
// Phase A: logits[8][2304] into LDS (q via wave-uniform scalar loads, k per-lane)
// Phase B: exact row softmax (wave per 2 rows), write attn weights to d_out
// Phase C: PV accumulate from LDS p, coalesced v reads; write ctx [b][s][h*64+d]
// ---------------------------------------------------------------------------
__global__ __launch_bounds__(256) void attn_kernel(
    const float* __restrict__ qp, const float* __restrict__ kp,
    const float* __restrict__ vp, float* __restrict__ attn_out,
    float* __restrict__ ctx)
{
    __shared__ __align__(16) float pl[QROWS][LSTRIDE];   // 73,856 B
    __shared__ __align__(16) float cscr[2][QROWS][DD];   //  4,096 B

    const int t  = threadIdx.x;
    const int qt = blockIdx.x;           // 0..287
    const int h  = blockIdx.y;
    const int b  = blockIdx.z;
    const int s0 = qt * QROWS;

    const size_t headoff = ((size_t)(b * NH + h)) * SS * DD;
    const float* kbase = kp + headoff;
    const float* vbase = vp + headoff;
    const float* qbase = qp + headoff + (size_t)s0 * DD;   // wave-uniform reads

    // ---- Phase A: logits ----
    const float scale = 0.125f;   // 1/sqrt(64)
    for (int m = 0; m < 9; ++m) {
        const int j = t + 256 * m;
        const float4* krow = (const float4*)(kbase + (size_t)j * DD);
        float acc[QROWS];
        #pragma unroll
        for (int r = 0; r < QROWS; ++r) acc[r] = 0.f;
        #pragma unroll 4
        for (int c = 0; c < 16; ++c) {
            float4 kv = krow[c];
            #pragma unroll
            for (int r = 0; r < QROWS; ++r) {
                float4 qv = *(const float4*)(qbase + r * DD + 4 * c); // uniform -> s_load
                acc[r] += qv.x * kv.x + qv.y * kv.y + qv.z * kv.z + qv.w * kv.w;
            }
        }
        #pragma unroll
        for (int r = 0; r < QROWS; ++r) pl[r][j] = acc[r] * scale;
    }
    __syncthreads();

    // ---- Phase B: softmax (wave w handles rows 2w, 2w+1) ----
    const int wave = t >> 6, lane = t & 63;
    for (int r = wave * 2; r < wave * 2 + 2; ++r) {
        float mx = -3.4e38f;
        #pragma unroll 6
        for (int m = 0; m < 36; ++m) mx = fmaxf(mx, pl[r][lane + 64 * m]);
        #pragma unroll
        for (int off = 32; off; off >>= 1) mx = fmaxf(mx, __shfl_xor(mx, off));
        float sum = 0.f;
        #pragma unroll 6
        for (int m = 0; m < 36; ++m) {
            float p = __expf(pl[r][lane + 64 * m] - mx);
            pl[r][lane + 64 * m] = p;
            sum += p;
        }
        #pragma unroll
        for (int off = 32; off; off >>= 1) sum += __shfl_xor(sum, off);
        const float inv = 1.0f / sum;
        float* arow = attn_out + ((size_t)((b * NH + h) * SS + s0 + r)) * SS;
        #pragma unroll 6
        for (int m = 0; m < 36; ++m) {
            float p = pl[r][lane + 64 * m] * inv;
            pl[r][lane + 64 * m] = p;
            arow[lane + 64 * m] = p;
        }
    }
    __syncthreads();

    // ---- Phase C: PV ----
    {
        const int r  = t >> 5;          // 0..7
        const int sub = t & 31;
        const int dg  = sub & 15;       // float4 group within d
        const int kh  = sub >> 4;       // key half
        const int jbase = kh * 1152;
        float4 acc = make_float4(0.f, 0.f, 0.f, 0.f);
        for (int jj = 0; jj < 1152; jj += 4) {
            float4 p4 = *(const float4*)&pl[r][jbase + jj];
            const float* vr = vbase + (size_t)(jbase + jj) * DD + 4 * dg;
            float4 v0 = *(const float4*)(vr);
            float4 v1 = *(const float4*)(vr + DD);
            float4 v2 = *(const float4*)(vr + 2 * DD);
            float4 v3 = *(const float4*)(vr + 3 * DD);
            acc.x += p4.x * v0.x + p4.y * v1.x + p4.z * v2.x + p4.w * v3.x;
            acc.y += p4.x * v0.y + p4.y * v1.y + p4.z * v2.y + p4.w * v3.y;
            acc.z += p4.x * v0.z + p4.y * v1.z + p4.z * v2.z + p4.w * v3.z;
            acc.w += p4.x * v0.w + p4.y * v1.w + p4.z * v2.w + p4.w * v3.w;
        }
        *(float4*)&cscr[kh][r][4 * dg] = acc;
    }
    __syncthreads();
    if (t < 128) {
        const int r2 = t >> 4, dg2 = t & 15;
        float4 x0 = *(const float4*)&cscr[0][r2][4 * dg2];
        float4 x1 = *(const float4*)&cscr[1][r2][4 * dg2];
        float4 o = make_float4(x0.x + x1.x, x0.y + x1.y, x0.z + x1.z, x0.w + x1.w);
        *(float4*)&ctx[((size_t)b * SS + s0 + r2) * FF + h * DD + 4 * dg2] = o;
    }
}

extern "C" void kernel_launch(void* const* d_in, const int* in_sizes, int n_in,
                              void* d_out, int out_size, void* d_ws, size_t ws_size,
                              hipStream_t stream) {
    (void)in_sizes; (void)n_in; (void)out_size; (void)ws_size;
    const float* query = (const float*)d_in[0];
    const float* value = (const float*)d_in[1];   // NOTE: value is input 1
    const float* keys  = (const float*)d_in[2];
    const float* wq_w  = (const float*)d_in[3];
    const float* wq_b  = (const float*)d_in[4];
    const float* wk_w  = (const float*)d_in[5];
    const float* wk_b  = (const float*)d_in[6];
    const float* wv_w  = (const float*)d_in[7];
    const float* wv_b  = (const float*)d_in[8];
    const float* wo_w  = (const float*)d_in[9];
    const float* wo_b  = (const float*)d_in[10];

    float* out  = (float*)d_out;                       // [B,W,H,F] = 4,718,592 floats
    float* attn = out + (size_t)BB * SS * FF;          // [B,h,S,S] = 169,869,312 floats

    const size_t NQ = (size_t)BB * NH * SS * DD;       // 4,718,592
    float* ws  = (float*)d_ws;
    float* qp  = ws;
    float* kp  = ws + NQ;
    float* vp  = ws + 2 * NQ;
    float* ctx = ws + 3 * NQ;                          // [B][S][F]

    dim3 gproj(BSR / 64, FF / 64, 1);
    proj_kernel<<<gproj, 256, 0, stream>>>(query, wq_w, wq_b, qp, 1);
    proj_kernel<<<gproj, 256, 0, stream>>>(keys,  wk_w, wk_b, kp, 1);
    proj_kernel<<<gproj, 256, 0, stream>>>(value, wv_w, wv_b, vp, 1);

    dim3 gattn(SS / QROWS, NH, BB);
    attn_kernel<<<gattn, 256, 0, stream>>>(qp, kp, vp, attn, ctx);

    proj_kernel<<<gproj, 256, 0, stream>>>(ctx, wo_w, wo_b, out, 0);
}

// Round 2
// 1181.118 us; speedup vs baseline: 1.8793x; 1.8793x over previous
//
#include <hip/hip_runtime.h>
#include <cstddef>

#define BB 4
#define SS 2304      // 48*48
#define FF 512
#define NH 8
#define DD 64
#define BSR (BB*SS)  // 9216 rows
#define QR 16        // q-rows per attn block
#define LSTRIDE 2308 // 2304 + 4 pad (floats)

typedef __attribute__((ext_vector_type(8))) short bf16x8;
typedef __attribute__((ext_vector_type(4))) float f32x4;
#define MFMA16(a,b,c) __builtin_amdgcn_mfma_f32_16x16x32_bf16((a),(b),(c),0,0,0)

__device__ __forceinline__ ushort f2bf_rne(float x) {
    uint u = __float_as_uint(x);
    uint r = u + 0x7fffu + ((u >> 16) & 1u);
    return (ushort)(r >> 16);
}

// ---------------------------------------------------------------------------
// Projection GEMM: out = X @ W + b (fp32, unchanged from round 1)
// ---------------------------------------------------------------------------
__global__ __launch_bounds__(256) void proj_kernel(
    const float* __restrict__ X, const float* __restrict__ Wm,
    const float* __restrict__ bias, float* __restrict__ out, int head_split)
{
    __shared__ __align__(16) float Ast[16][68];
    __shared__ __align__(16) float Bs[16][68];

    const int t  = threadIdx.x;
    const int i0 = blockIdx.x * 64;
    const int j0 = blockIdx.y * 64;
    const int tr = t >> 4;
    const int tc = t & 15;

    float4 acc[4];
    #pragma unroll
    for (int i = 0; i < 4; ++i) acc[i] = make_float4(0.f, 0.f, 0.f, 0.f);

    const int lrow = t >> 2;
    const int lcg  = t & 3;
    const int brow = t >> 4;
    const int bcg  = t & 15;

    for (int kk = 0; kk < FF; kk += 16) {
        float4 a = *(const float4*)&X[(size_t)(i0 + lrow) * FF + kk + 4 * lcg];
        Ast[4 * lcg + 0][lrow] = a.x;
        Ast[4 * lcg + 1][lrow] = a.y;
        Ast[4 * lcg + 2][lrow] = a.z;
        Ast[4 * lcg + 3][lrow] = a.w;
        float4 b = *(const float4*)&Wm[(size_t)(kk + brow) * FF + j0 + 4 * bcg];
        *(float4*)&Bs[brow][4 * bcg] = b;
        __syncthreads();
        #pragma unroll
        for (int k = 0; k < 16; ++k) {
            float4 av = *(const float4*)&Ast[k][4 * tr];
            float4 bv = *(const float4*)&Bs[k][4 * tc];
            acc[0].x += av.x * bv.x; acc[0].y += av.x * bv.y; acc[0].z += av.x * bv.z; acc[0].w += av.x * bv.w;
            acc[1].x += av.y * bv.x; acc[1].y += av.y * bv.y; acc[1].z += av.y * bv.z; acc[1].w += av.y * bv.w;
            acc[2].x += av.z * bv.x; acc[2].y += av.z * bv.y; acc[2].z += av.z * bv.z; acc[2].w += av.z * bv.w;
            acc[3].x += av.w * bv.x; acc[3].y += av.w * bv.y; acc[3].z += av.w * bv.z; acc[3].w += av.w * bv.w;
        }
        __syncthreads();
    }

    float4 bb = *(const float4*)&bias[j0 + 4 * tc];
    #pragma unroll
    for (int i = 0; i < 4; ++i) {
        const int row = i0 + 4 * tr + i;
        float4 o = make_float4(acc[i].x + bb.x, acc[i].y + bb.y,
                               acc[i].z + bb.z, acc[i].w + bb.w);
        if (head_split) {
            const int bidx = row / SS;
            const int s    = row - bidx * SS;
            const int head = j0 >> 6;
            *(float4*)&out[(((size_t)bidx * NH + head) * SS + s) * DD + 4 * tc] = o;
        } else {
            *(float4*)&out[(size_t)row * FF + j0 + 4 * tc] = o;
        }
    }
}

// ---------------------------------------------------------------------------
// Split fp32 -> bf16 hi/lo (same layout)
// ---------------------------------------------------------------------------
__global__ __launch_bounds__(256) void split_kernel(
    const float* __restrict__ in, ushort* __restrict__ hi, ushort* __restrict__ lo)
{
    const int i = blockIdx.x * 256 + threadIdx.x;
    float4 x = ((const float4*)in)[i];
    ushort4 h, lw;
    h.x = f2bf_rne(x.x); lw.x = f2bf_rne(x.x - __uint_as_float((uint)h.x << 16));
    h.y = f2bf_rne(x.y); lw.y = f2bf_rne(x.y - __uint_as_float((uint)h.y << 16));
    h.z = f2bf_rne(x.z); lw.z = f2bf_rne(x.z - __uint_as_float((uint)h.z << 16));
    h.w = f2bf_rne(x.w); lw.w = f2bf_rne(x.w - __uint_as_float((uint)h.w << 16));
    ((ushort4*)hi)[i] = h;
    ((ushort4*)lo)[i] = lw;
}

// ---------------------------------------------------------------------------
// V transpose+split: v[bh][s][d] -> vt{hi,lo}[bh][d][s]
// ---------------------------------------------------------------------------
__global__ __launch_bounds__(256) void vtsplit_kernel(
    const float* __restrict__ v, ushort* __restrict__ vthi, ushort* __restrict__ vtlo)
{
    __shared__ __align__(16) float tile[64][68];
    const int t  = threadIdx.x;
    const int st = blockIdx.x;   // s-tile (36)
    const int bh = blockIdx.y;   // 32
    {
        const int r  = t >> 2;
        const int cg = (t & 3) * 16;
        const float* src = v + ((size_t)bh * SS + st * 64 + r) * DD + cg;
        #pragma unroll
        for (int j = 0; j < 4; ++j)
            *(float4*)&tile[r][cg + 4 * j] = *(const float4*)(src + 4 * j);
    }
    __syncthreads();
    {
        const int d  = t >> 2;
        const int sg = (t & 3) * 16;
        union { ushort s[16]; uint4 q[2]; } H, L;
        #pragma unroll
        for (int j = 0; j < 16; ++j) {
            float x = tile[sg + j][d];
            ushort hh = f2bf_rne(x);
            H.s[j] = hh;
            L.s[j] = f2bf_rne(x - __uint_as_float((uint)hh << 16));
        }
        size_t off = ((size_t)bh * DD + d) * SS + st * 64 + sg;
        *(uint4*)(vthi + off)     = H.q[0];
        *(uint4*)(vthi + off + 8) = H.q[1];
        *(uint4*)(vtlo + off)     = L.q[0];
        *(uint4*)(vtlo + off + 8) = L.q[1];
    }
}

// ---------------------------------------------------------------------------
// Attention: block = (16 q-rows, head, batch), 512 threads (8 waves).
// Phase A: QK^T via split-bf16 MFMA -> fp32 logits strip in LDS
// Phase B: exact softmax, write attn weights, pack p to bf16 hi/lo in place
// Phase C: PV via split-bf16 MFMA, cross-wave combine, write ctx
// ---------------------------------------------------------------------------
__global__ __launch_bounds__(512) void attn_kernel(
    const ushort* __restrict__ qhi, const ushort* __restrict__ qlo,
    const ushort* __restrict__ khi, const ushort* __restrict__ klo,
    const ushort* __restrict__ vthi, const ushort* __restrict__ vtlo,
    float* __restrict__ attn_out, float* __restrict__ ctx)
{
    __shared__ __align__(16) float pl[QR][LSTRIDE];   // 147,712 B

    const int t  = threadIdx.x;
    const int w  = t >> 6;
    const int l  = t & 63;
    const int qt = blockIdx.x;
    const int h  = blockIdx.y;
    const int b  = blockIdx.z;
    const int s0 = qt * QR;
    const int bh = b * NH + h;
    const size_t base = (size_t)bh * SS * DD;
    const int ar = l & 15;          // fragment row (m for A, n for B)
    const int kg = (l >> 4) * 8;    // k offset within 32-chunk

    // ---- Phase A: QK^T ----
    const size_t qo = base + (size_t)(s0 + ar) * DD + kg;
    const bf16x8 qh0 = *(const bf16x8*)(qhi + qo);
    const bf16x8 qh1 = *(const bf16x8*)(qhi + qo + 32);
    const bf16x8 ql0 = *(const bf16x8*)(qlo + qo);
    const bf16x8 ql1 = *(const bf16x8*)(qlo + qo + 32);

    for (int i = 0; i < 18; i += 2) {
        const int ct0 = w + 8 * i, ct1 = ct0 + 8;
        const size_t ko0 = base + (size_t)(ct0 * 16 + ar) * DD + kg;
        const size_t ko1 = base + (size_t)(ct1 * 16 + ar) * DD + kg;
        bf16x8 kh00 = *(const bf16x8*)(khi + ko0);
        bf16x8 kh01 = *(const bf16x8*)(khi + ko0 + 32);
        bf16x8 kl00 = *(const bf16x8*)(klo + ko0);
        bf16x8 kl01 = *(const bf16x8*)(klo + ko0 + 32);
        bf16x8 kh10 = *(const bf16x8*)(khi + ko1);
        bf16x8 kh11 = *(const bf16x8*)(khi + ko1 + 32);
        bf16x8 kl10 = *(const bf16x8*)(klo + ko1);
        bf16x8 kl11 = *(const bf16x8*)(klo + ko1 + 32);
        f32x4 a0 = {0.f, 0.f, 0.f, 0.f}, a1 = {0.f, 0.f, 0.f, 0.f};
        a0 = MFMA16(qh0, kh00, a0); a1 = MFMA16(qh0, kh10, a1);
        a0 = MFMA16(qh1, kh01, a0); a1 = MFMA16(qh1, kh11, a1);
        a0 = MFMA16(qh0, kl00, a0); a1 = MFMA16(qh0, kl10, a1);
        a0 = MFMA16(qh1, kl01, a0); a1 = MFMA16(qh1, kl11, a1);
        a0 = MFMA16(ql0, kh00, a0); a1 = MFMA16(ql0, kh10, a1);
        a0 = MFMA16(ql1, kh01, a0); a1 = MFMA16(ql1, kh11, a1);
        #pragma unroll
        for (int r = 0; r < 4; ++r) {
            const int m = (l >> 4) * 4 + r;
            pl[m][ct0 * 16 + ar] = a0[r] * 0.125f;
            pl[m][ct1 * 16 + ar] = a1[r] * 0.125f;
        }
    }
    __syncthreads();

    // ---- Phase B: softmax (wave w -> rows 2w, 2w+1) ----
    #pragma unroll
    for (int rr = 0; rr < 2; ++rr) {
        const int r = w * 2 + rr;
        float mx = -3.4e38f;
        #pragma unroll 9
        for (int m = 0; m < 36; ++m) mx = fmaxf(mx, pl[r][l + 64 * m]);
        #pragma unroll
        for (int off = 32; off; off >>= 1) mx = fmaxf(mx, __shfl_xor(mx, off));
        float sum = 0.f;
        #pragma unroll 9
        for (int m = 0; m < 36; ++m) {
            float p = __expf(pl[r][l + 64 * m] - mx);
            pl[r][l + 64 * m] = p;
            sum += p;
        }
        #pragma unroll
        for (int off = 32; off; off >>= 1) sum += __shfl_xor(sum, off);
        const float inv = 1.0f / sum;
        float* arow = attn_out + ((size_t)bh * SS + s0 + r) * SS;
        uint* plu = (uint*)&pl[r][0];
        #pragma unroll 9
        for (int m = 0; m < 36; ++m) {
            float p = pl[r][l + 64 * m] * inv;
            arow[l + 64 * m] = p;
            uint hi = (uint)f2bf_rne(p);
            float rem = p - __uint_as_float(hi << 16);
            uint lo = (uint)f2bf_rne(rem);
            plu[l + 64 * m] = (hi << 16) | lo;
        }
    }
    __syncthreads();

    // ---- Phase C: PV ----
    const int dt = w & 3, khalf = w >> 2;
    const int d0 = dt * 16;
    const uint* parow = (const uint*)&pl[0][0] + ar * LSTRIDE + kg;
    const size_t vo = ((size_t)bh * DD + d0 + ar) * SS + kg;
    f32x4 acc0 = {0.f, 0.f, 0.f, 0.f}, acc1 = {0.f, 0.f, 0.f, 0.f};

    union U8 { uint u[4]; bf16x8 v; };
    for (int ii = 0; ii < 36; ii += 2) {
        const int c0 = (khalf * 36 + ii) * 32;
        const int c1 = c0 + 32;
        uint4 A0 = *(const uint4*)(parow + c0);
        uint4 A1 = *(const uint4*)(parow + c0 + 4);
        uint4 B0 = *(const uint4*)(parow + c1);
        uint4 B1 = *(const uint4*)(parow + c1 + 4);
        bf16x8 vh0 = *(const bf16x8*)(vthi + vo + c0);
        bf16x8 vl0 = *(const bf16x8*)(vtlo + vo + c0);
        bf16x8 vh1 = *(const bf16x8*)(vthi + vo + c1);
        bf16x8 vl1 = *(const bf16x8*)(vtlo + vo + c1);
        U8 ah0, al0, ah1, al1;
        ah0.u[0] = (A0.x >> 16) | (A0.y & 0xffff0000u);
        ah0.u[1] = (A0.z >> 16) | (A0.w & 0xffff0000u);
        ah0.u[2] = (A1.x >> 16) | (A1.y & 0xffff0000u);
        ah0.u[3] = (A1.z >> 16) | (A1.w & 0xffff0000u);
        al0.u[0] = (A0.x & 0xffffu) | (A0.y << 16);
        al0.u[1] = (A0.z & 0xffffu) | (A0.w << 16);
        al0.u[2] = (A1.x & 0xffffu) | (A1.y << 16);
        al0.u[3] = (A1.z & 0xffffu) | (A1.w << 16);
        ah1.u[0] = (B0.x >> 16) | (B0.y & 0xffff0000u);
        ah1.u[1] = (B0.z >> 16) | (B0.w & 0xffff0000u);
        ah1.u[2] = (B1.x >> 16) | (B1.y & 0xffff0000u);
        ah1.u[3] = (B1.z >> 16) | (B1.w & 0xffff0000u);
        al1.u[0] = (B0.x & 0xffffu) | (B0.y << 16);
        al1.u[1] = (B0.z & 0xffffu) | (B0.w << 16);
        al1.u[2] = (B1.x & 0xffffu) | (B1.y << 16);
        al1.u[3] = (B1.z & 0xffffu) | (B1.w << 16);
        acc0 = MFMA16(ah0.v, vh0, acc0);
        acc0 = MFMA16(ah0.v, vl0, acc0);
        acc0 = MFMA16(al0.v, vh0, acc0);
        acc1 = MFMA16(ah1.v, vh1, acc1);
        acc1 = MFMA16(ah1.v, vl1, acc1);
        acc1 = MFMA16(al1.v, vh1, acc1);
    }

    __syncthreads();   // all PV reads of the strip done; reuse as scratch
    {
        f32x4 accs = acc0 + acc1;
        float* part = &pl[0][0];   // [2][16][68]
        #pragma unroll
        for (int r = 0; r < 4; ++r) {
            const int m = (l >> 4) * 4 + r;
            part[(khalf * 16 + m) * 68 + d0 + ar] = accs[r];
        }
    }
    __syncthreads();
    if (t < 256) {
        const int m = t >> 4, dg = t & 15;
        const float* part = &pl[0][0];
        float4 x0 = *(const float4*)&part[m * 68 + 4 * dg];
        float4 x1 = *(const float4*)&part[(16 + m) * 68 + 4 * dg];
        float4 o = make_float4(x0.x + x1.x, x0.y + x1.y, x0.z + x1.z, x0.w + x1.w);
        *(float4*)&ctx[((size_t)b * SS + s0 + m) * FF + h * DD + 4 * dg] = o;
    }
}

extern "C" void kernel_launch(void* const* d_in, const int* in_sizes, int n_in,
                              void* d_out, int out_size, void* d_ws, size_t ws_size,
                              hipStream_t stream) {
    (void)in_sizes; (void)n_in; (void)out_size; (void)ws_size;
    const float* query = (const float*)d_in[0];
    const float* value = (const float*)d_in[1];
    const float* keys  = (const float*)d_in[2];
    const float* wq_w  = (const float*)d_in[3];
    const float* wq_b  = (const float*)d_in[4];
    const float* wk_w  = (const float*)d_in[5];
    const float* wk_b  = (const float*)d_in[6];
    const float* wv_w  = (const float*)d_in[7];
    const float* wv_b  = (const float*)d_in[8];
    const float* wo_w  = (const float*)d_in[9];
    const float* wo_b  = (const float*)d_in[10];

    float* out  = (float*)d_out;
    float* attn = out + (size_t)BB * SS * FF;

    const size_t NQ = (size_t)BB * NH * SS * DD;   // 4,718,592
    float*  stage = (float*)d_ws;                  // NQ floats, later ctx
    ushort* qhi  = (ushort*)((float*)d_ws + NQ);
    ushort* qlo  = qhi + NQ;
    ushort* khi  = qlo + NQ;
    ushort* klo  = khi + NQ;
    ushort* vthi = klo + NQ;
    ushort* vtlo = vthi + NQ;

    dim3 gproj(BSR / 64, FF / 64, 1);
    const int gsplit = (int)(NQ / 1024);           // 4608 blocks of 256 (x4 floats)
    dim3 gvt(SS / 64, BB * NH, 1);
    dim3 gattn(SS / QR, NH, BB);

    proj_kernel<<<gproj, 256, 0, stream>>>(query, wq_w, wq_b, stage, 1);
    split_kernel<<<gsplit, 256, 0, stream>>>(stage, qhi, qlo);
    proj_kernel<<<gproj, 256, 0, stream>>>(keys, wk_w, wk_b, stage, 1);
    split_kernel<<<gsplit, 256, 0, stream>>>(stage, khi, klo);
    proj_kernel<<<gproj, 256, 0, stream>>>(value, wv_w, wv_b, stage, 1);
    vtsplit_kernel<<<gvt, 256, 0, stream>>>(stage, vthi, vtlo);

    attn_kernel<<<gattn, 512, 0, stream>>>(qhi, qlo, khi, klo, vthi, vtlo, attn, stage);

    proj_kernel<<<gproj, 256, 0, stream>>>(stage, wo_w, wo_b, out, 0);
}